// Round 13
// baseline (623.406 us; speedup 1.0000x reference)
//
#include <hip/hip_runtime.h>
#include <cstdint>
#include <cstddef>

// Problem constants
#define B_  256
#define S_  128
#define D_  1024
#define H_  8
#define DH_ 128
#define M_  (B_ * S_)   // 32768 rows

typedef _Float16 half8 __attribute__((ext_vector_type(8)));
typedef float    f32x4 __attribute__((ext_vector_type(4)));

#define GLOAD_LDS16(gp, lp)                                                    \
    __builtin_amdgcn_global_load_lds(                                          \
        (const __attribute__((address_space(1))) void*)(gp),                   \
        (__attribute__((address_space(3))) void*)(lp), 16, 0, 0)

// ---------------------------------------------------------------------------
// Conversion kernels (unchanged)
// ---------------------------------------------------------------------------
__global__ __launch_bounds__(256)
void cvt_code(const float* __restrict__ src, _Float16* __restrict__ dst, int n8)
{
    int i = blockIdx.x * 256 + threadIdx.x;
    if (i >= n8) return;
    const float4* s = (const float4*)src;
    float4 a = s[2 * i], b = s[2 * i + 1];
    half8 o;
    o[0] = (_Float16)a.x; o[1] = (_Float16)a.y; o[2] = (_Float16)a.z; o[3] = (_Float16)a.w;
    o[4] = (_Float16)b.x; o[5] = (_Float16)b.y; o[6] = (_Float16)b.z; o[7] = (_Float16)b.w;
    *(half8*)(dst + (size_t)i * 8) = o;
}

__global__ __launch_bounds__(256)
void cvt_wqkv(const float* __restrict__ Wq, const float* __restrict__ Wk,
              const float* __restrict__ Wv,
              const float* __restrict__ bq, const float* __restrict__ bk,
              const float* __restrict__ bv,
              _Float16* __restrict__ Wt, float* __restrict__ bias_all)
{
    int idx = blockIdx.x * 256 + threadIdx.x;   // 3072*128
    if (idx >= 3072 * 128) return;
    int n = idx >> 7, kc = idx & 127, k = kc * 8;
    int qkv = n >> 10, hf = n & 1023, h = hf >> 7, f = hf & 127;
    const float* W = (qkv == 0 ? Wq : (qkv == 1 ? Wk : Wv))
                     + (size_t)h * D_ * DH_ + (size_t)k * DH_ + f;
    half8 o;
    #pragma unroll
    for (int j = 0; j < 8; ++j) o[j] = (_Float16)W[(size_t)j * DH_];
    *(half8*)(Wt + (size_t)n * 1024 + k) = o;
    if (kc == 0)
        bias_all[n] = (qkv == 0 ? bq : (qkv == 1 ? bk : bv))[h * DH_ + f];
}

__global__ __launch_bounds__(256)
void cvt_wo(const float* __restrict__ Wo, _Float16* __restrict__ Wot)
{
    int idx = blockIdx.x * 256 + threadIdx.x;   // 1024*256
    if (idx >= 1024 * 256) return;
    int n = idx >> 8, kc = idx & 255, k = kc * 8;
    const float* W = Wo + (size_t)k * 1024 + n;
    half8 o;
    #pragma unroll
    for (int j = 0; j < 8; ++j) o[j] = (_Float16)W[(size_t)j * 1024];
    *(half8*)(Wot + (size_t)n * 2048 + k) = o;
}

// ---------------------------------------------------------------------------
// ROUND 13: 128x256 block tile, BK=32, 4 waves of 64x128 each (256 threads).
// Rationale (R12 counters): R12 was LDS-read-bound (96 reads x 12cyc = 1152-
// 1536 cyc/CU-tile-pair vs MFMA 1241) with 8-way bank conflicts on 64B rows.
// Fix 1: 64x128 wave tile -> fragment reuse 5.3x -> LDS feed 79 B/cyc < 85.
// Fix 2: granule swizzle for 64B rows: pos = lg ^ ((row>>1)&3) covers all 8
// bank-quads over 8 rows (2 lanes each = free). Source pre-swizzled (#21).
// R8 full-tile-prefetch skeleton: vmcnt(0)+barrier at tile head (full-tile
// cover), stage t+1 immediately after, no mid-tile publication waits.
// ---------------------------------------------------------------------------
template <bool OUTF32>
__global__ __launch_bounds__(256, 2)
void gemm_f16_w128(const _Float16* __restrict__ A1p, const _Float16* __restrict__ A2p,
                   int K1, const _Float16* __restrict__ Bt,
                   const float* __restrict__ bias, void* __restrict__ outp,
                   int Ntot, int Ktot, int ntn)
{
    __shared__ __align__(16) char lds[49152];   // 2 buf x (8 KB A + 16 KB B)

    const int tid = threadIdx.x;
    const int w = tid >> 6, l = tid & 63;
    const int wm = w >> 1, wn = w & 1;          // 2M x 2N wave grid
    const int lr = l & 15, lg = l >> 4;

    // Bijective XCD swizzle (grid % 8 == 0), n-fastest decode.
    const int cpx = gridDim.x >> 3;
    const int bid = blockIdx.x;
    const int swz = (bid & 7) * cpx + (bid >> 3);
    const int m0 = (swz / ntn) * 128, n0 = (swz % ntn) * 256;

    const int NT = Ktot >> 5;

    // Staging lane geometry: lane l covers row (chunk*16 + (l>>2)),
    // LDS granule (l&3). Source granule = g_lds ^ ((row>>1)&3).
    const int rr = l >> 2, gl = l & 3;

    auto stage = [&](int bufi, int t) {
        const int k0 = t << 5;
        char* base = lds + bufi * 24576;
        // A: 128 rows x 64B = 8 chunks of 16 rows; wave w does chunks w, w+4.
        {
            const _Float16* Asrc; int kc;
            if (k0 < K1) { Asrc = A1p; kc = k0; } else { Asrc = A2p; kc = k0 - K1; }
            #pragma unroll
            for (int i = 0; i < 2; ++i) {
                const int c = i * 4 + w;
                const int row = c * 16 + rr;
                const int gcol = (gl ^ ((row >> 1) & 3)) * 8;
                const _Float16* g = Asrc + (size_t)(m0 + row) * 1024 + kc + gcol;
                GLOAD_LDS16(g, base + c * 1024);
            }
        }
        // B: 256 rows = 16 chunks; wave w does chunks w, w+4, w+8, w+12.
        #pragma unroll
        for (int i = 0; i < 4; ++i) {
            const int c = i * 4 + w;
            const int row = c * 16 + rr;
            const int gcol = (gl ^ ((row >> 1) & 3)) * 8;
            const _Float16* g = Bt + (size_t)(n0 + row) * Ktot + k0 + gcol;
            GLOAD_LDS16(g, base + 8192 + c * 1024);
        }
    };

    auto ldA = [&](int bufi, int fi) -> half8 {
        const int row = wm * 64 + fi * 16 + lr;
        const int pos = lg ^ ((row >> 1) & 3);
        return *(const half8*)(lds + bufi * 24576 + row * 64 + pos * 16);
    };
    auto ldB = [&](int bufi, int fj) -> half8 {
        const int row = wn * 128 + fj * 16 + lr;
        const int pos = lg ^ ((row >> 1) & 3);
        return *(const half8*)(lds + bufi * 24576 + 8192 + row * 64 + pos * 16);
    };

    f32x4 acc[4][8] = {};

    stage(0, 0);

    for (int t = 0; t < NT; ++t) {
        const int buf = t & 1;
        const bool nl = (t + 1 < NT);

        // Publication: tile t's 6 loads were issued one full tile ago.
        asm volatile("s_waitcnt vmcnt(0)" ::: "memory");
        __builtin_amdgcn_s_barrier();

        if (nl) stage(buf ^ 1, t + 1);

        half8 af[4], bf[8];
        #pragma unroll
        for (int i = 0; i < 4; ++i) af[i] = ldA(buf, i);
        #pragma unroll
        for (int j = 0; j < 8; ++j) bf[j] = ldB(buf, j);

        __builtin_amdgcn_s_setprio(1);
        #pragma unroll
        for (int i = 0; i < 4; ++i)
            #pragma unroll
            for (int j = 0; j < 8; ++j)
                acc[i][j] = __builtin_amdgcn_mfma_f32_16x16x32_f16(
                    af[i], bf[j], acc[i][j], 0, 0, 0);
        __builtin_amdgcn_s_setprio(0);
        // WAR safe without a second barrier: a wave's buf reads complete
        // before its MFMAs, which complete before the next tile-head barrier.
    }

    // Epilogue: bias + relu + store
    #pragma unroll
    for (int i = 0; i < 4; ++i) {
        #pragma unroll
        for (int j = 0; j < 8; ++j) {
            const int n = n0 + wn * 128 + j * 16 + lr;
            const float bs = bias[n];
            #pragma unroll
            for (int rg = 0; rg < 4; ++rg) {
                const int m = m0 + wm * 64 + i * 16 + lg * 4 + rg;
                float v = acc[i][j][rg] + bs;
                v = v > 0.0f ? v : 0.0f;
                if constexpr (OUTF32)
                    ((float*)outp)[(size_t)m * Ntot + n] = v;
                else
                    ((_Float16*)outp)[(size_t)m * Ntot + n] = (_Float16)v;
            }
        }
    }
}

// ---------------------------------------------------------------------------
// Attention (Round-9 structure, measured; kept frozen).
// ---------------------------------------------------------------------------
__global__ __launch_bounds__(256, 2)
void attn_pdg_mfma(const _Float16* __restrict__ QKV, const float* __restrict__ Rel,
                   _Float16* __restrict__ resh)
{
    __shared__ __align__(16) char smem[75776];
    unsigned* rbits = (unsigned*)(smem + 70656);
    float* rowpart  = (float*)(smem + 72704);
    float* colpart  = (float*)(smem + 73728);
    float* inv_in   = (float*)(smem + 74752);
    float* inv_out  = (float*)(smem + 75264);

    const int tid = threadIdx.x;
    const int w = tid >> 6, l = tid & 63;
    const int wr = w >> 1, wc = w & 1;
    const int lr = l & 15, lg = l >> 4;
    const int h = blockIdx.x, b = blockIdx.y;

    for (int s = w; s < S_; s += 4) {
        const float* row = &Rel[((size_t)b * S_ + s) * S_];
        unsigned long long b0m = __ballot(row[l] > 0.5f);
        unsigned long long b1m = __ballot(row[64 + l] > 0.5f);
        if (l == 0) {
            rbits[s * 4 + 0] = (unsigned)b0m; rbits[s * 4 + 1] = (unsigned)(b0m >> 32);
            rbits[s * 4 + 2] = (unsigned)b1m; rbits[s * 4 + 3] = (unsigned)(b1m >> 32);
        }
    }

    const size_t gbase = (size_t)(b * S_) * 3072 + h * DH_;

    const _Float16* Vb = QKV + gbase + 2048;
    const int vrow = tid >> 1, vcol0 = (tid & 1) * 64;
    uint4 vreg[8];
    #pragma unroll
    for (int j = 0; j < 8; ++j)
        vreg[j] = *(const uint4*)&Vb[(size_t)vrow * 3072 + vcol0 + j * 8];

    #pragma unroll
    for (int i = 0; i < 8; ++i) {
        const int row = (w * 8 + i) * 4 + (l >> 4);
        const int gsrc = (l & 15) ^ (row & 7);
        const _Float16* gq = QKV + gbase + (size_t)row * 3072 + gsrc * 8;
        GLOAD_LDS16(gq, smem + (w * 8 + i) * 1024);
        const _Float16* gk = QKV + gbase + 1024 + (size_t)row * 3072 + gsrc * 8;
        GLOAD_LDS16(gk, smem + 32768 + (w * 8 + i) * 1024);
    }
    __syncthreads();

    f32x4 acc[4][4] = {};
    #pragma unroll
    for (int kc = 0; kc < 4; ++kc) {
        half8 af[4], bf[4];
        #pragma unroll
        for (int i = 0; i < 4; ++i) {
            const int row = wr * 64 + i * 16 + lr;
            const int pos = (kc * 4 + lg) ^ (row & 7);
            af[i] = *(const half8*)(smem + row * 256 + pos * 16);
        }
        #pragma unroll
        for (int j = 0; j < 4; ++j) {
            const int row = wc * 64 + j * 16 + lr;
            const int pos = (kc * 4 + lg) ^ (row & 7);
            bf[j] = *(const half8*)(smem + 32768 + row * 256 + pos * 16);
        }
        #pragma unroll
        for (int i = 0; i < 4; ++i)
            #pragma unroll
            for (int j = 0; j < 4; ++j)
                acc[i][j] = __builtin_amdgcn_mfma_f32_16x16x32_f16(af[i], bf[j], acc[i][j], 0, 0, 0);
    }

    auto relf = [&](int s, int t) -> float {
        float r;
        if (h < H_ / 2) {
            r = (float)((rbits[s * 4 + (t >> 5)] >> (t & 31)) & 1u);
            if (s == t) r += (float)h;
        } else {
            r = (float)((rbits[t * 4 + (s >> 5)] >> (s & 31)) & 1u);
        }
        return r;
    };

    f32x4 p[4][4];
    #pragma unroll
    for (int i = 0; i < 4; ++i)
        #pragma unroll
        for (int j = 0; j < 4; ++j)
            #pragma unroll
            for (int rg = 0; rg < 4; ++rg) {
                const int s = wr * 64 + i * 16 + lg * 4 + rg;
                const int t = wc * 64 + j * 16 + lr;
                p[i][j][rg] = relf(s, t) * acc[i][j][rg] + 1e-11f;
            }

    #pragma unroll
    for (int i = 0; i < 4; ++i)
        #pragma unroll
        for (int rg = 0; rg < 4; ++rg) {
            float part = p[i][0][rg] + p[i][1][rg] + p[i][2][rg] + p[i][3][rg];
            part += __shfl_xor(part, 1);
            part += __shfl_xor(part, 2);
            part += __shfl_xor(part, 4);
            part += __shfl_xor(part, 8);
            if (lr == 0) rowpart[wc * 128 + wr * 64 + i * 16 + lg * 4 + rg] = part;
        }
    #pragma unroll
    for (int j = 0; j < 4; ++j) {
        float part = 0.0f;
        #pragma unroll
        for (int i = 0; i < 4; ++i)
            part += p[i][j][0] + p[i][j][1] + p[i][j][2] + p[i][j][3];
        part += __shfl_xor(part, 16);
        part += __shfl_xor(part, 32);
        if (lg == 0) colpart[wr * 128 + wc * 64 + j * 16 + lr] = part;
    }
    __syncthreads();

    if (tid < 128) {
        inv_in[tid] = rsqrtf(colpart[tid] + colpart[128 + tid]);
    } else {
        const int s = tid - 128;
        inv_out[s] = rsqrtf(rowpart[s] + rowpart[128 + s]);
    }
    __syncthreads();

    float itj[4];
    #pragma unroll
    for (int j = 0; j < 4; ++j) itj[j] = inv_in[wc * 64 + j * 16 + lr];
    #pragma unroll
    for (int i = 0; i < 4; ++i)
        #pragma unroll
        for (int rg = 0; rg < 4; ++rg) {
            const int s = wr * 64 + i * 16 + lg * 4 + rg;
            const float os = inv_out[s];
            #pragma unroll
            for (int j = 0; j < 4; ++j) {
                const int t = wc * 64 + j * 16 + lr;
                const float val = relf(s, t) * p[i][j][rg] * itj[j] * os;
                *(_Float16*)(smem + s * 272 + t * 2) = (_Float16)val;
            }
        }

    #pragma unroll
    for (int j = 0; j < 8; ++j) {
        union { uint4 u; _Float16 hh[8]; } uu;
        uu.u = vreg[j];
        #pragma unroll
        for (int e = 0; e < 8; ++e) {
            const int f = vcol0 + j * 8 + e;
            *(_Float16*)(smem + 34816 + f * 280 + vrow * 2) = uu.hh[e];
        }
    }
    __syncthreads();

    f32x4 acc2[4][4] = {};
    #pragma unroll
    for (int kc = 0; kc < 4; ++kc) {
        half8 af[4], bf[4];
        #pragma unroll
        for (int i = 0; i < 4; ++i)
            af[i] = *(const half8*)(smem + (wr * 64 + i * 16 + lr) * 272 + kc * 64 + lg * 16);
        #pragma unroll
        for (int j = 0; j < 4; ++j)
            bf[j] = *(const half8*)(smem + 34816 + (wc * 64 + j * 16 + lr) * 280 + kc * 64 + lg * 16);
        #pragma unroll
        for (int i = 0; i < 4; ++i)
            #pragma unroll
            for (int j = 0; j < 4; ++j)
                acc2[i][j] = __builtin_amdgcn_mfma_f32_16x16x32_f16(af[i], bf[j], acc2[i][j], 0, 0, 0);
    }

    #pragma unroll
    for (int i = 0; i < 4; ++i)
        #pragma unroll
        for (int rg = 0; rg < 4; ++rg) {
            const int s = wr * 64 + i * 16 + lg * 4 + rg;
            #pragma unroll
            for (int j = 0; j < 4; ++j) {
                const int f = wc * 64 + j * 16 + lr;
                resh[((size_t)(b * S_ + s)) * 1024 + h * DH_ + f] = (_Float16)acc2[i][j][rg];
            }
        }
}

// ---------------------------------------------------------------------------
extern "C" void kernel_launch(void* const* d_in, const int* in_sizes, int n_in,
                              void* d_out, int out_size, void* d_ws, size_t ws_size,
                              hipStream_t stream)
{
    const float* code = (const float*)d_in[0];
    const float* Rel  = (const float*)d_in[1];
    const float* Wq   = (const float*)d_in[2];
    const float* bq   = (const float*)d_in[3];
    const float* Wk   = (const float*)d_in[4];
    const float* bk   = (const float*)d_in[5];
    const float* Wv   = (const float*)d_in[6];
    const float* bv   = (const float*)d_in[7];
    const float* Wo   = (const float*)d_in[8];
    const float* bo   = (const float*)d_in[9];
    float* out = (float*)d_out;
    (void)in_sizes; (void)n_in; (void)out_size; (void)ws_size;

    char* wsp = (char*)d_ws;
    _Float16* codeh = (_Float16*)wsp;  wsp += (size_t)M_ * 1024 * 2;
    _Float16* QKV   = (_Float16*)wsp;  wsp += (size_t)M_ * 3072 * 2;
    _Float16* resh  = (_Float16*)wsp;  wsp += (size_t)M_ * 1024 * 2;
    _Float16* Wt    = (_Float16*)wsp;  wsp += (size_t)3072 * 1024 * 2;
    _Float16* Wot   = (_Float16*)wsp;  wsp += (size_t)1024 * 2048 * 2;
    float* bias_all = (float*)wsp;     wsp += 3072 * 4;

    cvt_code<<<(M_ * 1024 / 8 + 255) / 256, 256, 0, stream>>>(code, codeh, M_ * 1024 / 8);
    cvt_wqkv<<<(3072 * 128 + 255) / 256, 256, 0, stream>>>(Wq, Wk, Wv, bq, bk, bv, Wt, bias_all);
    cvt_wo<<<(1024 * 256 + 255) / 256, 256, 0, stream>>>(Wo, Wot);

    // QKV projection: [M,1024] x [1024,3072] -> QKV f16 [M][3072]
    gemm_f16_w128<false><<<(M_ / 128) * (3072 / 256), 256, 0, stream>>>(
        codeh, codeh, 1024, Wt, bias_all, (void*)QKV, 3072, 1024, 3072 / 256);

    attn_pdg_mfma<<<dim3(H_, B_), 256, 0, stream>>>(QKV, Rel, resh);

    // Output projection: [M, 2048(=resh|codeh)] x [2048,1024] -> out f32
    gemm_f16_w128<true><<<(M_ / 128) * (1024 / 256), 256, 0, stream>>>(
        resh, codeh, 1024, Wot, bo, (void*)out, 1024, 2048, 1024 / 256);
}

// Round 14
// 584.155 us; speedup vs baseline: 1.0672x; 1.0672x over previous
//
#include <hip/hip_runtime.h>
#include <cstdint>
#include <cstddef>

// Problem constants
#define B_  256
#define S_  128
#define D_  1024
#define H_  8
#define DH_ 128
#define M_  (B_ * S_)   // 32768 rows

typedef _Float16 half8 __attribute__((ext_vector_type(8)));
typedef float    f32x4 __attribute__((ext_vector_type(4)));

#define GLOAD_LDS16(gp, lp)                                                    \
    __builtin_amdgcn_global_load_lds(                                          \
        (const __attribute__((address_space(1))) void*)(gp),                   \
        (__attribute__((address_space(3))) void*)(lp), 16, 0, 0)

// ---------------------------------------------------------------------------
// Conversion kernels (unchanged)
// ---------------------------------------------------------------------------
__global__ __launch_bounds__(256)
void cvt_code(const float* __restrict__ src, _Float16* __restrict__ dst, int n8)
{
    int i = blockIdx.x * 256 + threadIdx.x;
    if (i >= n8) return;
    const float4* s = (const float4*)src;
    float4 a = s[2 * i], b = s[2 * i + 1];
    half8 o;
    o[0] = (_Float16)a.x; o[1] = (_Float16)a.y; o[2] = (_Float16)a.z; o[3] = (_Float16)a.w;
    o[4] = (_Float16)b.x; o[5] = (_Float16)b.y; o[6] = (_Float16)b.z; o[7] = (_Float16)b.w;
    *(half8*)(dst + (size_t)i * 8) = o;
}

__global__ __launch_bounds__(256)
void cvt_wqkv(const float* __restrict__ Wq, const float* __restrict__ Wk,
              const float* __restrict__ Wv,
              const float* __restrict__ bq, const float* __restrict__ bk,
              const float* __restrict__ bv,
              _Float16* __restrict__ Wt, float* __restrict__ bias_all)
{
    int idx = blockIdx.x * 256 + threadIdx.x;   // 3072*128
    if (idx >= 3072 * 128) return;
    int n = idx >> 7, kc = idx & 127, k = kc * 8;
    int qkv = n >> 10, hf = n & 1023, h = hf >> 7, f = hf & 127;
    const float* W = (qkv == 0 ? Wq : (qkv == 1 ? Wk : Wv))
                     + (size_t)h * D_ * DH_ + (size_t)k * DH_ + f;
    half8 o;
    #pragma unroll
    for (int j = 0; j < 8; ++j) o[j] = (_Float16)W[(size_t)j * DH_];
    *(half8*)(Wt + (size_t)n * 1024 + k) = o;
    if (kc == 0)
        bias_all[n] = (qkv == 0 ? bq : (qkv == 1 ? bk : bv))[h * DH_ + f];
}

__global__ __launch_bounds__(256)
void cvt_wo(const float* __restrict__ Wo, _Float16* __restrict__ Wot)
{
    int idx = blockIdx.x * 256 + threadIdx.x;   // 1024*256
    if (idx >= 1024 * 256) return;
    int n = idx >> 8, kc = idx & 255, k = kc * 8;
    const float* W = Wo + (size_t)k * 1024 + n;
    half8 o;
    #pragma unroll
    for (int j = 0; j < 8; ++j) o[j] = (_Float16)W[(size_t)j * 1024];
    *(half8*)(Wot + (size_t)n * 2048 + k) = o;
}

// ---------------------------------------------------------------------------
// ROUND 14: faithful m201 8-phase schedule. 256x256, BK=64, 8 waves (2Mx4N),
// 512 threads, 128 KiB LDS (2 buf x (32K A + 32K B)).
// KEY FIX vs R5-R8: staged chunks are PERMUTED to match phase read sets:
//   A slots  = rows with bits 6<->7 swapped  -> AQ1 read only at p1, AQ2 at p3
//   B slots  = rows with bit5->bit7 rotated  -> BQ1 read at p1&p4, BQ2 at p2
// Stage exactly 1 chunk/phase, each region overwritten exactly 1 phase after
// its last read; vmcnt(6) ONLY at p4/p8 (3-phase issue-to-wait cover); reads
// issued BEFORE the phase barrier (published >=1 phase earlier - verified).
// Phases per iteration (tiles u=2I buf0, u+1 buf1):
//  p1 rd{A(q0),B(q0)}u  st BQ1(u+1)      p5 rd{A(q0),B(q0)}u+1 st BQ1(u+2)
//  p2 rd{B(q1)}u        st AQ1(u+2)      p6 rd{B(q1)}u+1       st AQ1(u+3)
//  p3 rd{A(q1)}u        st BQ2(u+2)      p7 rd{A(q1)}u+1       st BQ2(u+3)
//  p4 rd{B(q0)}u        st AQ2(u+2) vm6  p8 rd{B(q0)}u+1       st AQ2(u+3) vm6
// ---------------------------------------------------------------------------
template <bool OUTF32>
__global__ __launch_bounds__(512, 1)
void gemm_f16_8p(const _Float16* __restrict__ A1p, const _Float16* __restrict__ A2p,
                 int K1, const _Float16* __restrict__ Bt,
                 const float* __restrict__ bias, void* __restrict__ outp,
                 int Ntot, int Ktot, int ntn)
{
    __shared__ __align__(16) char lds[131072];

    const int tid = threadIdx.x;
    const int w = tid >> 6, l = tid & 63;
    const int wm = w >> 2, wn = w & 3;
    const int lr = l & 15, lg = l >> 4;

    const int cpx = gridDim.x >> 3;
    const int bid = blockIdx.x;
    const int swz = (bid & 7) * cpx + (bid >> 3);
    const int m0 = (swz / ntn) * 256, n0 = (swz % ntn) * 256;

    const int NT = Ktot >> 6;
    const int NI = NT >> 1;

    const int srow8 = l >> 3;                    // slot low 3 bits
    const int gsw   = ((l & 7) ^ srow8) * 8;     // pre-swizzled source granule

    // chunks: 0=AQ1, 1=BQ2, 2=AQ2, 3=BQ1
    auto stageChunk = [&](int bufi, int t, int chunk) {
        const int k0 = t << 6;
        if (chunk == 0 || chunk == 2) {
            const _Float16* Asrc; int kc;
            if (k0 < K1) { Asrc = A1p; kc = k0; } else { Asrc = A2p; kc = k0 - K1; }
            char* dbase = lds + bufi * 65536 + (chunk == 2 ? 16384 : 0);
            const int soff = (chunk == 2 ? 128 : 0);
            #pragma unroll
            for (int i = 0; i < 2; ++i) {
                const int c = i * 8 + w;
                const int s = soff + c * 8 + srow8;
                const int srow = (s & 63) | (((s >> 6) & 1) << 7) | (((s >> 7) & 1) << 6);
                const _Float16* g = Asrc + (size_t)(m0 + srow) * 1024 + kc + gsw;
                GLOAD_LDS16(g, dbase + c * 1024);
            }
        } else {
            char* dbase = lds + bufi * 65536 + 32768 + (chunk == 1 ? 16384 : 0);
            const int soff = (chunk == 1 ? 128 : 0);
            #pragma unroll
            for (int i = 0; i < 2; ++i) {
                const int c = i * 8 + w;
                const int s = soff + c * 8 + srow8;
                const int srow = (s & 31) | (((s >> 5) & 3) << 6) | (((s >> 7) & 1) << 5);
                const _Float16* g = Bt + (size_t)(n0 + srow) * Ktot + k0 + gsw;
                GLOAD_LDS16(g, dbase + c * 1024);
            }
        }
    };

    half8 aq[4][2], b0[2][2], b1[2][2];
    f32x4 acc[8][4] = {};

    auto rdA = [&](int bufi, int qm) {
        #pragma unroll
        for (int f = 0; f < 4; ++f)
            #pragma unroll
            for (int ks = 0; ks < 2; ++ks) {
                const int slot = qm * 128 + wm * 64 + f * 16 + lr;
                const int pos = (ks * 4 + lg) ^ (lr & 7);
                aq[f][ks] = *(const half8*)(lds + bufi * 65536 + slot * 128 + pos * 16);
            }
    };
    auto rdB = [&](half8 bb[2][2], int bufi, int qn) {
        #pragma unroll
        for (int f = 0; f < 2; ++f)
            #pragma unroll
            for (int ks = 0; ks < 2; ++ks) {
                const int slot = qn * 128 + wn * 32 + f * 16 + lr;
                const int pos = (ks * 4 + lg) ^ (lr & 7);
                bb[f][ks] = *(const half8*)(lds + bufi * 65536 + 32768 + slot * 128 + pos * 16);
            }
    };
    auto mm16 = [&](half8 bb[2][2], int qm, int qn) {
        #pragma unroll
        for (int ks = 0; ks < 2; ++ks)
            #pragma unroll
            for (int f = 0; f < 4; ++f)
                #pragma unroll
                for (int j = 0; j < 2; ++j)
                    acc[qm * 4 + f][qn * 2 + j] = __builtin_amdgcn_mfma_f32_16x16x32_f16(
                        aq[f][ks], bb[j][ks], acc[qm * 4 + f][qn * 2 + j], 0, 0, 0);
    };

#define PHASE_TAIL()                                              \
    __builtin_amdgcn_s_barrier();                                 \
    asm volatile("s_waitcnt lgkmcnt(0)" ::: "memory");            \
    __builtin_amdgcn_sched_barrier(0);                            \
    __builtin_amdgcn_s_setprio(1)

#define PHASE_END()                                               \
    __builtin_amdgcn_s_setprio(0);                                \
    __builtin_amdgcn_s_barrier();                                 \
    __builtin_amdgcn_sched_barrier(0)

    // Prologue: tile0 all 4 chunks, tile1 chunks {AQ1,BQ2,AQ2}; vmcnt(6)
    // guarantees tile0 fully landed (14 issued, <=6 outstanding).
    stageChunk(0, 0, 0); stageChunk(0, 0, 1); stageChunk(0, 0, 2); stageChunk(0, 0, 3);
    stageChunk(1, 1, 0); stageChunk(1, 1, 1); stageChunk(1, 1, 2);
    asm volatile("s_waitcnt vmcnt(6)" ::: "memory");
    __builtin_amdgcn_s_barrier();
    __builtin_amdgcn_sched_barrier(0);

    for (int I = 0; I < NI; ++I) {
        const int u = 2 * I;
        const bool nl = (I + 1 < NI);

        // p1
        rdA(0, 0); rdB(b0, 0, 0);
        stageChunk(1, u + 1, 3);
        PHASE_TAIL(); mm16(b0, 0, 0); PHASE_END();
        // p2
        rdB(b1, 0, 1);
        if (nl) stageChunk(0, u + 2, 0);
        PHASE_TAIL(); mm16(b1, 0, 1); PHASE_END();
        // p3
        rdA(0, 1);
        if (nl) stageChunk(0, u + 2, 1);
        PHASE_TAIL(); mm16(b1, 1, 1); PHASE_END();
        // p4
        rdB(b0, 0, 0);
        if (nl) {
            stageChunk(0, u + 2, 2);
            asm volatile("s_waitcnt vmcnt(6)" ::: "memory");
        } else {
            asm volatile("s_waitcnt vmcnt(0)" ::: "memory");
        }
        PHASE_TAIL(); mm16(b0, 1, 0); PHASE_END();
        // p5
        rdA(1, 0); rdB(b0, 1, 0);
        if (nl) stageChunk(0, u + 2, 3);
        PHASE_TAIL(); mm16(b0, 0, 0); PHASE_END();
        // p6
        rdB(b1, 1, 1);
        if (nl) stageChunk(1, u + 3, 0);
        PHASE_TAIL(); mm16(b1, 0, 1); PHASE_END();
        // p7
        rdA(1, 1);
        if (nl) stageChunk(1, u + 3, 1);
        PHASE_TAIL(); mm16(b1, 1, 1); PHASE_END();
        // p8
        rdB(b0, 1, 0);
        if (nl) {
            stageChunk(1, u + 3, 2);
            asm volatile("s_waitcnt vmcnt(6)" ::: "memory");
        }
        PHASE_TAIL(); mm16(b0, 1, 0); PHASE_END();
    }
#undef PHASE_TAIL
#undef PHASE_END

    // Epilogue: bias + relu + store
    #pragma unroll
    for (int fi = 0; fi < 8; ++fi) {
        #pragma unroll
        for (int fj = 0; fj < 4; ++fj) {
            const int n = n0 + wn * 64 + fj * 16 + lr;
            const float bs = bias[n];
            #pragma unroll
            for (int rg = 0; rg < 4; ++rg) {
                const int m = m0 + wm * 128 + fi * 16 + lg * 4 + rg;
                float v = acc[fi][fj][rg] + bs;
                v = v > 0.0f ? v : 0.0f;
                if constexpr (OUTF32)
                    ((float*)outp)[(size_t)m * Ntot + n] = v;
                else
                    ((_Float16*)outp)[(size_t)m * Ntot + n] = (_Float16)v;
            }
        }
    }
}

// ---------------------------------------------------------------------------
// Attention (Round-9 structure, measured; kept frozen).
// ---------------------------------------------------------------------------
__global__ __launch_bounds__(256, 2)
void attn_pdg_mfma(const _Float16* __restrict__ QKV, const float* __restrict__ Rel,
                   _Float16* __restrict__ resh)
{
    __shared__ __align__(16) char smem[75776];
    unsigned* rbits = (unsigned*)(smem + 70656);
    float* rowpart  = (float*)(smem + 72704);
    float* colpart  = (float*)(smem + 73728);
    float* inv_in   = (float*)(smem + 74752);
    float* inv_out  = (float*)(smem + 75264);

    const int tid = threadIdx.x;
    const int w = tid >> 6, l = tid & 63;
    const int wr = w >> 1, wc = w & 1;
    const int lr = l & 15, lg = l >> 4;
    const int h = blockIdx.x, b = blockIdx.y;

    for (int s = w; s < S_; s += 4) {
        const float* row = &Rel[((size_t)b * S_ + s) * S_];
        unsigned long long b0m = __ballot(row[l] > 0.5f);
        unsigned long long b1m = __ballot(row[64 + l] > 0.5f);
        if (l == 0) {
            rbits[s * 4 + 0] = (unsigned)b0m; rbits[s * 4 + 1] = (unsigned)(b0m >> 32);
            rbits[s * 4 + 2] = (unsigned)b1m; rbits[s * 4 + 3] = (unsigned)(b1m >> 32);
        }
    }

    const size_t gbase = (size_t)(b * S_) * 3072 + h * DH_;

    const _Float16* Vb = QKV + gbase + 2048;
    const int vrow = tid >> 1, vcol0 = (tid & 1) * 64;
    uint4 vreg[8];
    #pragma unroll
    for (int j = 0; j < 8; ++j)
        vreg[j] = *(const uint4*)&Vb[(size_t)vrow * 3072 + vcol0 + j * 8];

    #pragma unroll
    for (int i = 0; i < 8; ++i) {
        const int row = (w * 8 + i) * 4 + (l >> 4);
        const int gsrc = (l & 15) ^ (row & 7);
        const _Float16* gq = QKV + gbase + (size_t)row * 3072 + gsrc * 8;
        GLOAD_LDS16(gq, smem + (w * 8 + i) * 1024);
        const _Float16* gk = QKV + gbase + 1024 + (size_t)row * 3072 + gsrc * 8;
        GLOAD_LDS16(gk, smem + 32768 + (w * 8 + i) * 1024);
    }
    __syncthreads();

    f32x4 acc[4][4] = {};
    #pragma unroll
    for (int kc = 0; kc < 4; ++kc) {
        half8 af[4], bf[4];
        #pragma unroll
        for (int i = 0; i < 4; ++i) {
            const int row = wr * 64 + i * 16 + lr;
            const int pos = (kc * 4 + lg) ^ (row & 7);
            af[i] = *(const half8*)(smem + row * 256 + pos * 16);
        }
        #pragma unroll
        for (int j = 0; j < 4; ++j) {
            const int row = wc * 64 + j * 16 + lr;
            const int pos = (kc * 4 + lg) ^ (row & 7);
            bf[j] = *(const half8*)(smem + 32768 + row * 256 + pos * 16);
        }
        #pragma unroll
        for (int i = 0; i < 4; ++i)
            #pragma unroll
            for (int j = 0; j < 4; ++j)
                acc[i][j] = __builtin_amdgcn_mfma_f32_16x16x32_f16(af[i], bf[j], acc[i][j], 0, 0, 0);
    }

    auto relf = [&](int s, int t) -> float {
        float r;
        if (h < H_ / 2) {
            r = (float)((rbits[s * 4 + (t >> 5)] >> (t & 31)) & 1u);
            if (s == t) r += (float)h;
        } else {
            r = (float)((rbits[t * 4 + (s >> 5)] >> (s & 31)) & 1u);
        }
        return r;
    };

    f32x4 p[4][4];
    #pragma unroll
    for (int i = 0; i < 4; ++i)
        #pragma unroll
        for (int j = 0; j < 4; ++j)
            #pragma unroll
            for (int rg = 0; rg < 4; ++rg) {
                const int s = wr * 64 + i * 16 + lg * 4 + rg;
                const int t = wc * 64 + j * 16 + lr;
                p[i][j][rg] = relf(s, t) * acc[i][j][rg] + 1e-11f;
            }

    #pragma unroll
    for (int i = 0; i < 4; ++i)
        #pragma unroll
        for (int rg = 0; rg < 4; ++rg) {
            float part = p[i][0][rg] + p[i][1][rg] + p[i][2][rg] + p[i][3][rg];
            part += __shfl_xor(part, 1);
            part += __shfl_xor(part, 2);
            part += __shfl_xor(part, 4);
            part += __shfl_xor(part, 8);
            if (lr == 0) rowpart[wc * 128 + wr * 64 + i * 16 + lg * 4 + rg] = part;
        }
    #pragma unroll
    for (int j = 0; j < 4; ++j) {
        float part = 0.0f;
        #pragma unroll
        for (int i = 0; i < 4; ++i)
            part += p[i][j][0] + p[i][j][1] + p[i][j][2] + p[i][j][3];
        part += __shfl_xor(part, 16);
        part += __shfl_xor(part, 32);
        if (lg == 0) colpart[wr * 128 + wc * 64 + j * 16 + lr] = part;
    }
    __syncthreads();

    if (tid < 128) {
        inv_in[tid] = rsqrtf(colpart[tid] + colpart[128 + tid]);
    } else {
        const int s = tid - 128;
        inv_out[s] = rsqrtf(rowpart[s] + rowpart[128 + s]);
    }
    __syncthreads();

    float itj[4];
    #pragma unroll
    for (int j = 0; j < 4; ++j) itj[j] = inv_in[wc * 64 + j * 16 + lr];
    #pragma unroll
    for (int i = 0; i < 4; ++i)
        #pragma unroll
        for (int rg = 0; rg < 4; ++rg) {
            const int s = wr * 64 + i * 16 + lg * 4 + rg;
            const float os = inv_out[s];
            #pragma unroll
            for (int j = 0; j < 4; ++j) {
                const int t = wc * 64 + j * 16 + lr;
                const float val = relf(s, t) * p[i][j][rg] * itj[j] * os;
                *(_Float16*)(smem + s * 272 + t * 2) = (_Float16)val;
            }
        }

    #pragma unroll
    for (int j = 0; j < 8; ++j) {
        union { uint4 u; _Float16 hh[8]; } uu;
        uu.u = vreg[j];
        #pragma unroll
        for (int e = 0; e < 8; ++e) {
            const int f = vcol0 + j * 8 + e;
            *(_Float16*)(smem + 34816 + f * 280 + vrow * 2) = uu.hh[e];
        }
    }
    __syncthreads();

    f32x4 acc2[4][4] = {};
    #pragma unroll
    for (int kc = 0; kc < 4; ++kc) {
        half8 af[4], bf[4];
        #pragma unroll
        for (int i = 0; i < 4; ++i)
            af[i] = *(const half8*)(smem + (wr * 64 + i * 16 + lr) * 272 + kc * 64 + lg * 16);
        #pragma unroll
        for (int j = 0; j < 4; ++j)
            bf[j] = *(const half8*)(smem + 34816 + (wc * 64 + j * 16 + lr) * 280 + kc * 64 + lg * 16);
        #pragma unroll
        for (int i = 0; i < 4; ++i)
            #pragma unroll
            for (int j = 0; j < 4; ++j)
                acc2[i][j] = __builtin_amdgcn_mfma_f32_16x16x32_f16(af[i], bf[j], acc2[i][j], 0, 0, 0);
    }

    #pragma unroll
    for (int i = 0; i < 4; ++i)
        #pragma unroll
        for (int rg = 0; rg < 4; ++rg) {
            const int s = wr * 64 + i * 16 + lg * 4 + rg;
            #pragma unroll
            for (int j = 0; j < 4; ++j) {
                const int f = wc * 64 + j * 16 + lr;
                resh[((size_t)(b * S_ + s)) * 1024 + h * DH_ + f] = (_Float16)acc2[i][j][rg];
            }
        }
}

// ---------------------------------------------------------------------------
extern "C" void kernel_launch(void* const* d_in, const int* in_sizes, int n_in,
                              void* d_out, int out_size, void* d_ws, size_t ws_size,
                              hipStream_t stream)
{
    const float* code = (const float*)d_in[0];
    const float* Rel  = (const float*)d_in[1];
    const float* Wq   = (const float*)d_in[2];
    const float* bq   = (const float*)d_in[3];
    const float* Wk   = (const float*)d_in[4];
    const float* bk   = (const float*)d_in[5];
    const float* Wv   = (const float*)d_in[6];
    const float* bv   = (const float*)d_in[7];
    const float* Wo   = (const float*)d_in[8];
    const float* bo   = (const float*)d_in[9];
    float* out = (float*)d_out;
    (void)in_sizes; (void)n_in; (void)out_size; (void)ws_size;

    char* wsp = (char*)d_ws;
    _Float16* codeh = (_Float16*)wsp;  wsp += (size_t)M_ * 1024 * 2;
    _Float16* QKV   = (_Float16*)wsp;  wsp += (size_t)M_ * 3072 * 2;
    _Float16* resh  = (_Float16*)wsp;  wsp += (size_t)M_ * 1024 * 2;
    _Float16* Wt    = (_Float16*)wsp;  wsp += (size_t)3072 * 1024 * 2;
    _Float16* Wot   = (_Float16*)wsp;  wsp += (size_t)1024 * 2048 * 2;
    float* bias_all = (float*)wsp;     wsp += 3072 * 4;

    cvt_code<<<(M_ * 1024 / 8 + 255) / 256, 256, 0, stream>>>(code, codeh, M_ * 1024 / 8);
    cvt_wqkv<<<(3072 * 128 + 255) / 256, 256, 0, stream>>>(Wq, Wk, Wv, bq, bk, bv, Wt, bias_all);
    cvt_wo<<<(1024 * 256 + 255) / 256, 256, 0, stream>>>(Wo, Wot);

    // QKV projection: [M,1024] x [1024,3072] -> QKV f16 [M][3072]
    gemm_f16_8p<false><<<(M_ / 256) * (3072 / 256), 512, 0, stream>>>(
        codeh, codeh, 1024, Wt, bias_all, (void*)QKV, 3072, 1024, 3072 / 256);

    attn_pdg_mfma<<<dim3(H_, B_), 256, 0, stream>>>(QKV, Rel, resh);

    // Output projection: [M, 2048(=resh|codeh)] x [2048,1024] -> out f32
    gemm_f16_8p<true><<<(M_ / 256) * (1024 / 256), 512, 0, stream>>>(
        resh, codeh, 1024, Wot, bo, (void*)out, 1024, 2048, 1024 / 256);
}